// Round 4
// baseline (3865.974 us; speedup 1.0000x reference)
//
#include <hip/hip_runtime.h>
#include <hip/hip_bf16.h>

// Problem constants
#define BB 4
#define TT 2048
#define DD 1024
#define HH 16
#define SS 64
#define CH 64
#define NC (TT/CH)        // 32
#define M_ROWS (BB*TT)    // 8192

typedef __hip_bfloat16 bf16;

static __device__ __forceinline__ float b2f(bf16 v) { return __bfloat162float(v); }

// ---- block-wide sum over 256 threads (deterministic tree) ----
static __device__ __forceinline__ float block_sum(float v, float* red) {
  int tid = threadIdx.x;
  red[tid] = v; __syncthreads();
  #pragma unroll
  for (int o = 128; o > 0; o >>= 1) {
    if (tid < o) red[tid] += red[tid + o];
    __syncthreads();
  }
  float r = red[0];
  __syncthreads();
  return r;
}

// ---- K1: per-matrix weight scale = clip(mean|w|, 1e-8) ----
__global__ __launch_bounds__(256) void k_wscale(const float* __restrict__ w,
                                                float* __restrict__ wscale) {
  __shared__ double red[256];
  int i = blockIdx.x, tid = threadIdx.x;
  const float* wi = w + (size_t)i * DD * DD;
  double s = 0.0;
  for (int j = tid; j < DD * DD; j += 256) s += (double)fabsf(wi[j]);
  red[tid] = s; __syncthreads();
  for (int o = 128; o > 0; o >>= 1) {
    if (tid < o) red[tid] += red[tid + o];
    __syncthreads();
  }
  if (tid == 0) wscale[i] = fmaxf((float)(red[0] * (1.0 / (DD * DD))), 1e-8f);
}

// ---- K2: ternary weight quant, stored as exact bf16 {-1,0,1} ----
__global__ __launch_bounds__(256) void k_wquant(const float* __restrict__ w,
                                                const float* __restrict__ wscale,
                                                bf16* __restrict__ wq) {
  int idx = blockIdx.x * 256 + threadIdx.x;   // < 5*1024*1024
  int i = idx >> 20;                          // / (DD*DD)
  float ws = wscale[i];
  float wn = w[idx] / ws;
  wn = fminf(fmaxf(wn, -1.f), 1.f);
  wq[idx] = __float2bfloat16(rintf(wn));      // round-half-even, matches jnp.round
}

// ---- K3: token-shift mix + LayerNorm + activation quant (projections r,k,v,g) ----
__global__ __launch_bounds__(256) void k_prep_quant(
    const float* __restrict__ x, const float* __restrict__ mu_r,
    const float* __restrict__ mu_k, const float* __restrict__ mu_v,
    const float* __restrict__ mu_g, const float* __restrict__ ln_g,
    const float* __restrict__ ln_b, bf16* __restrict__ xq,
    float* __restrict__ ascale) {
  __shared__ float red[256];
  int m = blockIdx.x, i = blockIdx.y, tid = threadIdx.x;
  int t = m & (TT - 1);
  const float* mu = (i == 0) ? mu_r : (i == 1) ? mu_k : (i == 2) ? mu_v : mu_g;
  const float* xr = x + (size_t)m * DD;
  const float* lg = ln_g + i * DD;
  const float* lb = ln_b + i * DD;
  float inp[4];
  #pragma unroll
  for (int j = 0; j < 4; j++) {
    int d = tid + j * 256;
    float xv = xr[d];
    float xs = (t > 0) ? xr[d - DD] : 0.f;
    inp[j] = xv + (xs - xv) * mu[d];
  }
  float mean = block_sum(inp[0] + inp[1] + inp[2] + inp[3], red) * (1.f / DD);
  float var = 0.f;
  #pragma unroll
  for (int j = 0; j < 4; j++) { float dv = inp[j] - mean; var += dv * dv; }
  var = block_sum(var, red) * (1.f / DD);
  float rstd = 1.f / sqrtf(var + 1e-5f);
  float ln[4]; float aabs = 0.f;
  #pragma unroll
  for (int j = 0; j < 4; j++) {
    int d = tid + j * 256;
    ln[j] = (inp[j] - mean) * rstd * lg[d] + lb[d];
    aabs += fabsf(ln[j]);
  }
  float meanabs = block_sum(aabs, red) * (1.f / DD);
  float scale = fmaxf(meanabs, 1e-8f) * 2.5f * (1.f / 127.f);
  bf16* xo = xq + ((size_t)i * M_ROWS + m) * DD;
  #pragma unroll
  for (int j = 0; j < 4; j++) {
    int d = tid + j * 256;
    float q = rintf(fminf(fmaxf(ln[j] / scale, -127.f), 127.f));
    xo[d] = __float2bfloat16(q);              // exact: |int| <= 127
  }
  if (tid == 0) ascale[i * M_ROWS + m] = scale;
}

// ---- K4/K9: VALU fp32 GEMM (correct-by-construction).
// out[m][n] = ascale[m]*wscale * sum_k A[m][k]*W[n][k].
// 64x64 tile/block, 256 threads, each thread a 4x4 sub-tile. Integer products
// (|xq|<=127, w in {-1,0,1}) accumulate exactly in fp32.
__global__ __launch_bounds__(256) void k_gemm_v(
    const bf16* __restrict__ Axq, const bf16* __restrict__ Wq,
    const float* __restrict__ ascale, const float* __restrict__ wscale,
    int projbase, float* __restrict__ outF) {
  __shared__ float As[64][33];   // +1 pad: kills power-of-2 bank stride
  __shared__ float Ws[64][33];
  int tid = threadIdx.x;
  int m0 = blockIdx.x * 64, n0 = blockIdx.y * 64;
  int z = blockIdx.z;
  int proj = projbase + z;
  const bf16* Ap = Axq + ((size_t)z * M_ROWS + m0) * DD;
  const bf16* Wp = Wq + ((size_t)proj * DD + n0) * DD;
  float acc[4][4] = {};
  int ty = tid >> 4, tx = tid & 15;           // rows m0+ty*4.., cols n0+tx*4..
  int lr = tid >> 2, lc = (tid & 3) * 8;      // staging: 8 elems/thread/matrix
  for (int k0 = 0; k0 < DD; k0 += 32) {
    #pragma unroll
    for (int q = 0; q < 8; q++) {
      As[lr][lc + q] = b2f(Ap[(size_t)lr * DD + k0 + lc + q]);
      Ws[lr][lc + q] = b2f(Wp[(size_t)lr * DD + k0 + lc + q]);
    }
    __syncthreads();
    #pragma unroll 8
    for (int kk = 0; kk < 32; kk++) {
      float av[4], wv2[4];
      #pragma unroll
      for (int i2 = 0; i2 < 4; i2++) av[i2] = As[ty * 4 + i2][kk];
      #pragma unroll
      for (int j2 = 0; j2 < 4; j2++) wv2[j2] = Ws[tx * 4 + j2][kk];
      #pragma unroll
      for (int i2 = 0; i2 < 4; i2++)
        #pragma unroll
        for (int j2 = 0; j2 < 4; j2++)
          acc[i2][j2] += av[i2] * wv2[j2];
    }
    __syncthreads();
  }
  const float* asc = ascale + (size_t)z * M_ROWS + m0;
  float wsc = wscale[proj];
  #pragma unroll
  for (int i2 = 0; i2 < 4; i2++) {
    int mm = ty * 4 + i2;
    float s = asc[mm] * wsc;
    #pragma unroll
    for (int j2 = 0; j2 < 4; j2++) {
      int nn = tx * 4 + j2;
      size_t idx = ((size_t)z * M_ROWS + m0 + mm) * DD + (n0 + nn);
      outF[idx] = acc[i2][j2] * s;
    }
  }
}

// ---- K5: per-chunk injection  inj[s,o] = sum_c w^{63-c} k[c,s] v[c,o] ----
__global__ __launch_bounds__(256) void k_inj(const float* __restrict__ rkvg,
                                             const float* __restrict__ log_decay,
                                             float* __restrict__ states) {
  __shared__ float ksh[CH * SS], vsh[CH * SS];
  int blk = blockIdx.x, tid = threadIdx.x;
  int n = blk & (NC - 1), h = (blk >> 5) & (HH - 1), b = blk >> 9;
  size_t rowbase = ((size_t)b * TT + n * CH) * DD + h * SS;
  const float* Kp = rkvg + (size_t)1 * M_ROWS * DD + rowbase;
  const float* Vp = rkvg + (size_t)2 * M_ROWS * DD + rowbase;
  for (int idx = tid; idx < CH * SS; idx += 256) {
    int c = idx >> 6, s2 = idx & 63;
    ksh[idx] = Kp[(size_t)c * DD + s2];
    vsh[idx] = Vp[(size_t)c * DD + s2];
  }
  int o = tid & 63, sg = tid >> 6;
  float wv[16], acc[16];
  #pragma unroll
  for (int j = 0; j < 16; j++) {
    int s2 = sg * 16 + j;
    float e = expf(log_decay[h * SS + s2]);
    wv[j] = expf(-e); acc[j] = 0.f;
  }
  __syncthreads();
  for (int c = 0; c < CH; c++) {
    float vvv = vsh[c * SS + o];
    #pragma unroll
    for (int j = 0; j < 16; j++)
      acc[j] = wv[j] * acc[j] + ksh[c * SS + sg * 16 + j] * vvv;
  }
  float* st = states + (size_t)blk * SS * SS;
  #pragma unroll
  for (int j = 0; j < 16; j++) st[(size_t)(sg * 16 + j) * SS + o] = acc[j];
}

// ---- K6: in-place scan: slot n := state entering chunk n; state' = w^64*state + inj ----
__global__ __launch_bounds__(256) void k_scan(const float* __restrict__ log_decay,
                                              float* __restrict__ states) {
  int bh = blockIdx.x, tid = threadIdx.x;
  int h = bh & (HH - 1);
  int o = tid & 63, sg = tid >> 6;
  float wC[16], cur[16];
  #pragma unroll
  for (int j = 0; j < 16; j++) {
    int s2 = sg * 16 + j;
    float e = expf(log_decay[h * SS + s2]);
    wC[j] = expf(-64.f * e);
    cur[j] = 0.f;
  }
  float* base = states + (size_t)bh * NC * SS * SS;
  for (int n = 0; n < NC; n++) {
    float* p = base + (size_t)n * SS * SS;
    #pragma unroll
    for (int j = 0; j < 16; j++) {
      size_t ii = (size_t)(sg * 16 + j) * SS + o;
      float inj = p[ii];
      p[ii] = cur[j];
      cur[j] = wC[j] * cur[j] + inj;
    }
  }
}

// ---- K7: per-chunk output. Pass A: suffix scan A[t]=kv[t]+w*A[t+1], y=r·A + beta*v.
//          Pass B: cross term y += (r*w^{t+1})·state. ----
__global__ __launch_bounds__(256) void k_wkv_y(const float* __restrict__ rkvg,
                                               const float* __restrict__ log_decay,
                                               const float* __restrict__ u,
                                               const float* __restrict__ states,
                                               float* __restrict__ Y) {
  __shared__ float rsh[CH * SS], ksh[CH * SS], vsh[CH * SS];
  __shared__ float beta[CH];
  __shared__ float part[4 * SS];
  int blk = blockIdx.x, tid = threadIdx.x;
  int n = blk & (NC - 1), h = (blk >> 5) & (HH - 1), b = blk >> 9;
  size_t rowbase = ((size_t)b * TT + n * CH) * DD + h * SS;
  const float* Rp = rkvg + rowbase;
  const float* Kp = rkvg + (size_t)1 * M_ROWS * DD + rowbase;
  const float* Vp = rkvg + (size_t)2 * M_ROWS * DD + rowbase;
  for (int idx = tid; idx < CH * SS; idx += 256) {
    int c = idx >> 6, s2 = idx & 63;
    rsh[idx] = Rp[(size_t)c * DD + s2];
    ksh[idx] = Kp[(size_t)c * DD + s2];
    vsh[idx] = Vp[(size_t)c * DD + s2];
  }
  int o = tid & 63, sg = tid >> 6;
  float wv[16], st[16];
  const float* stp = states + (size_t)blk * SS * SS;
  #pragma unroll
  for (int j = 0; j < 16; j++) {
    int s2 = sg * 16 + j;
    float e = expf(log_decay[h * SS + s2]);
    wv[j] = expf(-e);
    st[j] = stp[(size_t)s2 * SS + o];
  }
  __syncthreads();
  if (tid < CH) {
    float s = 0.f;
    for (int s2 = 0; s2 < SS; s2++)
      s += rsh[tid * SS + s2] * ksh[tid * SS + s2] * expf(u[h * SS + s2]);
    beta[tid] = s;
  }
  __syncthreads();
  float* Yb = Y + ((size_t)b * TT + n * CH) * DD + h * SS;
  float a[16];
  #pragma unroll
  for (int j = 0; j < 16; j++) a[j] = 0.f;
  for (int t = CH - 1; t >= 0; t--) {
    float vvv = vsh[t * SS + o];
    float p = 0.f;
    #pragma unroll
    for (int j = 0; j < 16; j++) {
      int s2 = sg * 16 + j;
      a[j] = ksh[t * SS + s2] * vvv + wv[j] * a[j];   // A[t] includes kv[t] (w^0)
      p += rsh[t * SS + s2] * a[j];
    }
    part[sg * SS + o] = p;
    __syncthreads();
    if (tid < SS) {
      float y = part[tid] + part[SS + tid] + part[2 * SS + tid] + part[3 * SS + tid]
              + beta[t] * vsh[t * SS + tid];
      Yb[(size_t)t * DD + tid] = y;
    }
    __syncthreads();
  }
  float pw[16];
  #pragma unroll
  for (int j = 0; j < 16; j++) pw[j] = wv[j];        // w^{t+1} at t=0
  for (int t = 0; t < CH; t++) {
    float p = 0.f;
    #pragma unroll
    for (int j = 0; j < 16; j++) {
      p += rsh[t * SS + sg * 16 + j] * pw[j] * st[j];
      pw[j] *= wv[j];
    }
    part[sg * SS + o] = p;
    __syncthreads();
    if (tid < SS)
      Yb[(size_t)t * DD + tid] += part[tid] + part[SS + tid] + part[2 * SS + tid] + part[3 * SS + tid];
    __syncthreads();
  }
}

// ---- K8: GroupNorm(H groups) + *silu(g) + LayerNorm + act-quant for final proj ----
__global__ __launch_bounds__(256) void k_post(const float* __restrict__ Y,
                                              const float* __restrict__ G,
                                              const float* __restrict__ gn_g,
                                              const float* __restrict__ gn_b,
                                              const float* __restrict__ lg,
                                              const float* __restrict__ lb,
                                              bf16* __restrict__ xq4,
                                              float* __restrict__ ascale4) {
  __shared__ float red[256];
  __shared__ float ysh[DD];
  __shared__ float gmean[HH], grstd[HH];
  int m = blockIdx.x, tid = threadIdx.x;
  const float* Yr = Y + (size_t)m * DD;
  const float* Gr = G + (size_t)m * DD;
  #pragma unroll
  for (int j = 0; j < 4; j++) { int d = tid + j * 256; ysh[d] = Yr[d]; }
  __syncthreads();
  if (tid < HH) {
    float s = 0.f;
    for (int q2 = 0; q2 < SS; q2++) s += ysh[tid * SS + ((q2 + tid * 4) & 63)];
    float mn = s * (1.f / SS);
    float v2 = 0.f;
    for (int q2 = 0; q2 < SS; q2++) {
      float dv = ysh[tid * SS + ((q2 + tid * 4) & 63)] - mn; v2 += dv * dv;
    }
    gmean[tid] = mn;
    grstd[tid] = 1.f / sqrtf(v2 * (1.f / SS) + 1e-5f);
  }
  __syncthreads();
  float z[4];
  #pragma unroll
  for (int j = 0; j < 4; j++) {
    int d = tid + j * 256; int hh = d >> 6;
    float yn = (ysh[d] - gmean[hh]) * grstd[hh] * gn_g[d] + gn_b[d];
    float gv = Gr[d];
    z[j] = yn * (gv / (1.f + expf(-gv)));            // silu
  }
  float mean = block_sum(z[0] + z[1] + z[2] + z[3], red) * (1.f / DD);
  float var = 0.f;
  #pragma unroll
  for (int j = 0; j < 4; j++) { float dv = z[j] - mean; var += dv * dv; }
  var = block_sum(var, red) * (1.f / DD);
  float rstd = 1.f / sqrtf(var + 1e-5f);
  float ln[4]; float aabs = 0.f;
  #pragma unroll
  for (int j = 0; j < 4; j++) {
    int d = tid + j * 256;
    ln[j] = (z[j] - mean) * rstd * lg[d] + lb[d];
    aabs += fabsf(ln[j]);
  }
  float meanabs = block_sum(aabs, red) * (1.f / DD);
  float scale = fmaxf(meanabs, 1e-8f) * 2.5f * (1.f / 127.f);
  #pragma unroll
  for (int j = 0; j < 4; j++) {
    int d = tid + j * 256;
    xq4[(size_t)m * DD + d] =
        __float2bfloat16(rintf(fminf(fmaxf(ln[j] / scale, -127.f), 127.f)));
  }
  if (tid == 0) ascale4[m] = scale;
}

extern "C" void kernel_launch(void* const* d_in, const int* in_sizes, int n_in,
                              void* d_out, int out_size, void* d_ws, size_t ws_size,
                              hipStream_t stream) {
  // ALL inputs are float32 (per the reference); output float32.
  const float* x         = (const float*)d_in[0];
  const float* mu_r      = (const float*)d_in[1];
  const float* mu_k      = (const float*)d_in[2];
  const float* mu_v      = (const float*)d_in[3];
  const float* mu_g      = (const float*)d_in[4];
  const float* log_decay = (const float*)d_in[5];
  const float* u         = (const float*)d_in[6];
  const float* proj_w    = (const float*)d_in[7];
  const float* ln_g      = (const float*)d_in[8];
  const float* ln_b      = (const float*)d_in[9];
  const float* gn_g      = (const float*)d_in[10];
  const float* gn_b      = (const float*)d_in[11];
  float* out = (float*)d_out;

  // ---- workspace layout, ~234 MiB total (R2/R3 ran it without faulting) ----
  // U region (64 MB) is time-multiplexed:
  //   phase 1: xq slots 0..3 (bf16, 4 x 16 MB)   [k_prep_quant -> k_gemm_v]
  //   phase 2: Y  (f32, 32 MB) at U+0            [k_wkv_y -> k_post]
  //            xq4 (bf16, 16 MB) at U+32MB       [k_post -> k_gemm_v final]
  char* p = (char*)d_ws;
  float* wscale = (float*)p;  p += 256;                         // 5 f32
  bf16*  wq     = (bf16*)p;   p += (size_t)5 * DD * DD * 2;     // 10 MB
  float* ascale = (float*)p;  p += (size_t)5 * M_ROWS * 4;      // 160 KB
  char*  U      = p;          p += (size_t)4 * M_ROWS * DD * 2; // 64 MB
  bf16*  xq     = (bf16*)U;
  float* Y      = (float*)U;
  bf16*  xq4    = (bf16*)(U + (size_t)M_ROWS * DD * 4);         // U + 32 MB
  float* rkvg   = (float*)p;  p += (size_t)4 * M_ROWS * DD * 4; // 128 MB
  float* states = (float*)p;  p += (size_t)BB * HH * NC * SS * SS * 4; // 32 MB

  hipLaunchKernelGGL(k_wscale, dim3(5), dim3(256), 0, stream, proj_w, wscale);
  hipLaunchKernelGGL(k_wquant, dim3((5 * DD * DD) / 256), dim3(256), 0, stream,
                     proj_w, wscale, wq);
  hipLaunchKernelGGL(k_prep_quant, dim3(M_ROWS, 4), dim3(256), 0, stream,
                     x, mu_r, mu_k, mu_v, mu_g, ln_g, ln_b, xq, ascale);
  hipLaunchKernelGGL(k_gemm_v, dim3(M_ROWS / 64, DD / 64, 4), dim3(256), 0,
                     stream, xq, wq, ascale, wscale, 0, rkvg);
  hipLaunchKernelGGL(k_inj, dim3(BB * HH * NC), dim3(256), 0, stream,
                     rkvg, log_decay, states);
  hipLaunchKernelGGL(k_scan, dim3(BB * HH), dim3(256), 0, stream, log_decay, states);
  hipLaunchKernelGGL(k_wkv_y, dim3(BB * HH * NC), dim3(256), 0, stream,
                     rkvg, log_decay, u, states, Y);
  hipLaunchKernelGGL(k_post, dim3(M_ROWS), dim3(256), 0, stream,
                     Y, rkvg + (size_t)3 * M_ROWS * DD, gn_g, gn_b,
                     ln_g + 4 * DD, ln_b + 4 * DD,
                     xq4, ascale + 4 * M_ROWS);
  hipLaunchKernelGGL(k_gemm_v, dim3(M_ROWS / 64, DD / 64, 1), dim3(256), 0,
                     stream, xq4, wq,
                     ascale + 4 * M_ROWS, wscale, 4, out);
}

// Round 5
// 650.264 us; speedup vs baseline: 5.9452x; 5.9452x over previous
//
#include <hip/hip_runtime.h>
#include <hip/hip_bf16.h>

// Problem constants
#define BB 4
#define TT 2048
#define DD 1024
#define HH 16
#define SS 64
#define CH 64
#define NC (TT/CH)        // 32
#define M_ROWS (BB*TT)    // 8192

typedef __hip_bfloat16 bf16;
using short8 = __attribute__((ext_vector_type(8))) short;   // 8 bf16 (4 VGPRs)
using f32x4  = __attribute__((ext_vector_type(4))) float;

static __device__ __forceinline__ float b2f(bf16 v) { return __bfloat162float(v); }

// ---- block-wide sum over 256 threads (deterministic tree) ----
static __device__ __forceinline__ float block_sum(float v, float* red) {
  int tid = threadIdx.x;
  red[tid] = v; __syncthreads();
  #pragma unroll
  for (int o = 128; o > 0; o >>= 1) {
    if (tid < o) red[tid] += red[tid + o];
    __syncthreads();
  }
  float r = red[0];
  __syncthreads();
  return r;
}

// ---- K1a: weight-scale partials. grid (5,64); block b sums a contiguous
// 16384-elem slice of matrix i into wpart[i*64+b]. Coalesced, parallel. ----
__global__ __launch_bounds__(256) void k_wscale_part(const float* __restrict__ w,
                                                     double* __restrict__ wpart) {
  __shared__ double red[256];
  int i = blockIdx.x, b = blockIdx.y, tid = threadIdx.x;
  const float* base = w + (size_t)i * DD * DD + (size_t)b * 16384;
  double s = 0.0;
  #pragma unroll
  for (int j = 0; j < 64; j++) s += (double)fabsf(base[tid + j * 256]);
  red[tid] = s; __syncthreads();
  for (int o = 128; o > 0; o >>= 1) {
    if (tid < o) red[tid] += red[tid + o];
    __syncthreads();
  }
  if (tid == 0) wpart[i * 64 + b] = red[0];
}

// ---- K1b: fold 64 partials per matrix in fixed order (deterministic) ----
__global__ __launch_bounds__(64) void k_wscale_fin(const double* __restrict__ wpart,
                                                   float* __restrict__ wscale) {
  int i = blockIdx.x;
  if (threadIdx.x == 0) {
    double s = 0.0;
    for (int b = 0; b < 64; b++) s += wpart[i * 64 + b];
    wscale[i] = fmaxf((float)(s * (1.0 / (DD * DD))), 1e-8f);
  }
}

// ---- K2: ternary weight quant, stored as exact bf16 {-1,0,1} ----
__global__ __launch_bounds__(256) void k_wquant(const float* __restrict__ w,
                                                const float* __restrict__ wscale,
                                                bf16* __restrict__ wq) {
  int idx = blockIdx.x * 256 + threadIdx.x;   // < 5*1024*1024
  int i = idx >> 20;                          // / (DD*DD)
  float ws = wscale[i];
  float wn = w[idx] / ws;
  wn = fminf(fmaxf(wn, -1.f), 1.f);
  wq[idx] = __float2bfloat16(rintf(wn));      // round-half-even, matches jnp.round
}

// ---- K3: token-shift mix + LayerNorm + activation quant (projections r,k,v,g) ----
__global__ __launch_bounds__(256) void k_prep_quant(
    const float* __restrict__ x, const float* __restrict__ mu_r,
    const float* __restrict__ mu_k, const float* __restrict__ mu_v,
    const float* __restrict__ mu_g, const float* __restrict__ ln_g,
    const float* __restrict__ ln_b, bf16* __restrict__ xq,
    float* __restrict__ ascale) {
  __shared__ float red[256];
  int m = blockIdx.x, i = blockIdx.y, tid = threadIdx.x;
  int t = m & (TT - 1);
  const float* mu = (i == 0) ? mu_r : (i == 1) ? mu_k : (i == 2) ? mu_v : mu_g;
  const float* xr = x + (size_t)m * DD;
  const float* lg = ln_g + i * DD;
  const float* lb = ln_b + i * DD;
  float inp[4];
  #pragma unroll
  for (int j = 0; j < 4; j++) {
    int d = tid + j * 256;
    float xv = xr[d];
    float xs = (t > 0) ? xr[d - DD] : 0.f;
    inp[j] = xv + (xs - xv) * mu[d];
  }
  float mean = block_sum(inp[0] + inp[1] + inp[2] + inp[3], red) * (1.f / DD);
  float var = 0.f;
  #pragma unroll
  for (int j = 0; j < 4; j++) { float dv = inp[j] - mean; var += dv * dv; }
  var = block_sum(var, red) * (1.f / DD);
  float rstd = 1.f / sqrtf(var + 1e-5f);
  float ln[4]; float aabs = 0.f;
  #pragma unroll
  for (int j = 0; j < 4; j++) {
    int d = tid + j * 256;
    ln[j] = (inp[j] - mean) * rstd * lg[d] + lb[d];
    aabs += fabsf(ln[j]);
  }
  float meanabs = block_sum(aabs, red) * (1.f / DD);
  float scale = fmaxf(meanabs, 1e-8f) * 2.5f * (1.f / 127.f);
  bf16* xo = xq + ((size_t)i * M_ROWS + m) * DD;
  #pragma unroll
  for (int j = 0; j < 4; j++) {
    int d = tid + j * 256;
    float q = rintf(fminf(fmaxf(ln[j] / scale, -127.f), 127.f));
    xo[d] = __float2bfloat16(q);              // exact: |int| <= 127
  }
  if (tid == 0) ascale[i * M_ROWS + m] = scale;
}

// ---- K4/K9: bf16 MFMA GEMM  out[m][n] = ascale[m]*wscale * sum_k A[m][k]*W[n][k]
// 64x64 tile/block, 4 waves, mfma_f32_16x16x32_bf16. Layout validated:
// R2(MFMA) == R3(VALU) bit-identical outputs on dense +-127 x ternary data. ----
__global__ __launch_bounds__(256) void k_gemm(
    const bf16* __restrict__ Axq, const bf16* __restrict__ Wq,
    const float* __restrict__ ascale, const float* __restrict__ wscale,
    int projbase, float* __restrict__ outF) {
  __shared__ short As[64][32];
  __shared__ short Bs[64][32];
  int tid = threadIdx.x;
  int wv = tid >> 6, lane = tid & 63;
  int m0 = blockIdx.x * 64, n0 = blockIdx.y * 64;
  int z = blockIdx.z;
  int proj = projbase + z;
  const bf16* Ap = Axq + ((size_t)z * M_ROWS + m0) * DD;
  const bf16* Wp = Wq + ((size_t)proj * DD + n0) * DD;
  const float* asc = ascale + (size_t)z * M_ROWS + m0;
  float wsc = wscale[proj];
  f32x4 acc[4];
  #pragma unroll
  for (int j = 0; j < 4; j++) acc[j] = (f32x4){0.f, 0.f, 0.f, 0.f};
  int lr = tid >> 2, lc = (tid & 3) * 8;      // staging: 16B per thread per tile
  int frow = lane & 15, fq = lane >> 4;
  for (int k0 = 0; k0 < DD; k0 += 32) {
    *(uint4*)&As[lr][lc] = *(const uint4*)&Ap[(size_t)lr * DD + k0 + lc];
    *(uint4*)&Bs[lr][lc] = *(const uint4*)&Wp[(size_t)lr * DD + k0 + lc];
    __syncthreads();
    short8 af = *(short8*)&As[16 * wv + frow][fq * 8];
    #pragma unroll
    for (int j = 0; j < 4; j++) {
      short8 bfr = *(short8*)&Bs[16 * j + frow][fq * 8];
      acc[j] = __builtin_amdgcn_mfma_f32_16x16x32_bf16(af, bfr, acc[j], 0, 0, 0);
    }
    __syncthreads();
  }
  int col = lane & 15, rg = lane >> 4;
  #pragma unroll
  for (int j = 0; j < 4; j++) {
    #pragma unroll
    for (int r = 0; r < 4; r++) {
      int mm = 16 * wv + rg * 4 + r;
      int nn = 16 * j + col;
      size_t idx = ((size_t)z * M_ROWS + m0 + mm) * DD + (n0 + nn);
      outF[idx] = acc[j][r] * asc[mm] * wsc;
    }
  }
}

// ---- K5: per-chunk injection  inj[s,o] = sum_c w^{63-c} k[c,s] v[c,o] ----
__global__ __launch_bounds__(256) void k_inj(const float* __restrict__ rkvg,
                                             const float* __restrict__ log_decay,
                                             float* __restrict__ states) {
  __shared__ float ksh[CH * SS], vsh[CH * SS];
  int blk = blockIdx.x, tid = threadIdx.x;
  int n = blk & (NC - 1), h = (blk >> 5) & (HH - 1), b = blk >> 9;
  size_t rowbase = ((size_t)b * TT + n * CH) * DD + h * SS;
  const float* Kp = rkvg + (size_t)1 * M_ROWS * DD + rowbase;
  const float* Vp = rkvg + (size_t)2 * M_ROWS * DD + rowbase;
  for (int idx = tid; idx < CH * SS; idx += 256) {
    int c = idx >> 6, s2 = idx & 63;
    ksh[idx] = Kp[(size_t)c * DD + s2];
    vsh[idx] = Vp[(size_t)c * DD + s2];
  }
  int o = tid & 63, sg = tid >> 6;
  float wv[16], acc[16];
  #pragma unroll
  for (int j = 0; j < 16; j++) {
    int s2 = sg * 16 + j;
    float e = expf(log_decay[h * SS + s2]);
    wv[j] = expf(-e); acc[j] = 0.f;
  }
  __syncthreads();
  for (int c = 0; c < CH; c++) {
    float vvv = vsh[c * SS + o];
    #pragma unroll
    for (int j = 0; j < 16; j++)
      acc[j] = wv[j] * acc[j] + ksh[c * SS + sg * 16 + j] * vvv;
  }
  float* st = states + (size_t)blk * SS * SS;
  #pragma unroll
  for (int j = 0; j < 16; j++) st[(size_t)(sg * 16 + j) * SS + o] = acc[j];
}

// ---- K6: in-place scan: slot n := state entering chunk n; state' = w^64*state + inj ----
__global__ __launch_bounds__(256) void k_scan(const float* __restrict__ log_decay,
                                              float* __restrict__ states) {
  int bh = blockIdx.x, tid = threadIdx.x;
  int h = bh & (HH - 1);
  int o = tid & 63, sg = tid >> 6;
  float wC[16], cur[16];
  #pragma unroll
  for (int j = 0; j < 16; j++) {
    int s2 = sg * 16 + j;
    float e = expf(log_decay[h * SS + s2]);
    wC[j] = expf(-64.f * e);
    cur[j] = 0.f;
  }
  float* base = states + (size_t)bh * NC * SS * SS;
  for (int n = 0; n < NC; n++) {
    float* p = base + (size_t)n * SS * SS;
    #pragma unroll
    for (int j = 0; j < 16; j++) {
      size_t ii = (size_t)(sg * 16 + j) * SS + o;
      float inj = p[ii];
      p[ii] = cur[j];
      cur[j] = wC[j] * cur[j] + inj;
    }
  }
}

// ---- K7: per-chunk output. Pass A: suffix scan A[t]=kv[t]+w*A[t+1], y=r·A + beta*v.
//          Pass B: cross term y += (r*w^{t+1})·state. ----
__global__ __launch_bounds__(256) void k_wkv_y(const float* __restrict__ rkvg,
                                               const float* __restrict__ log_decay,
                                               const float* __restrict__ u,
                                               const float* __restrict__ states,
                                               float* __restrict__ Y) {
  __shared__ float rsh[CH * SS], ksh[CH * SS], vsh[CH * SS];
  __shared__ float beta[CH];
  __shared__ float part[4 * SS];
  int blk = blockIdx.x, tid = threadIdx.x;
  int n = blk & (NC - 1), h = (blk >> 5) & (HH - 1), b = blk >> 9;
  size_t rowbase = ((size_t)b * TT + n * CH) * DD + h * SS;
  const float* Rp = rkvg + rowbase;
  const float* Kp = rkvg + (size_t)1 * M_ROWS * DD + rowbase;
  const float* Vp = rkvg + (size_t)2 * M_ROWS * DD + rowbase;
  for (int idx = tid; idx < CH * SS; idx += 256) {
    int c = idx >> 6, s2 = idx & 63;
    rsh[idx] = Rp[(size_t)c * DD + s2];
    ksh[idx] = Kp[(size_t)c * DD + s2];
    vsh[idx] = Vp[(size_t)c * DD + s2];
  }
  int o = tid & 63, sg = tid >> 6;
  float wv[16], st[16];
  const float* stp = states + (size_t)blk * SS * SS;
  #pragma unroll
  for (int j = 0; j < 16; j++) {
    int s2 = sg * 16 + j;
    float e = expf(log_decay[h * SS + s2]);
    wv[j] = expf(-e);
    st[j] = stp[(size_t)s2 * SS + o];
  }
  __syncthreads();
  if (tid < CH) {
    float s = 0.f;
    for (int s2 = 0; s2 < SS; s2++)
      s += rsh[tid * SS + s2] * ksh[tid * SS + s2] * expf(u[h * SS + s2]);
    beta[tid] = s;
  }
  __syncthreads();
  float* Yb = Y + ((size_t)b * TT + n * CH) * DD + h * SS;
  float a[16];
  #pragma unroll
  for (int j = 0; j < 16; j++) a[j] = 0.f;
  for (int t = CH - 1; t >= 0; t--) {
    float vvv = vsh[t * SS + o];
    float p = 0.f;
    #pragma unroll
    for (int j = 0; j < 16; j++) {
      int s2 = sg * 16 + j;
      a[j] = ksh[t * SS + s2] * vvv + wv[j] * a[j];   // A[t] includes kv[t] (w^0)
      p += rsh[t * SS + s2] * a[j];
    }
    part[sg * SS + o] = p;
    __syncthreads();
    if (tid < SS) {
      float y = part[tid] + part[SS + tid] + part[2 * SS + tid] + part[3 * SS + tid]
              + beta[t] * vsh[t * SS + tid];
      Yb[(size_t)t * DD + tid] = y;
    }
    __syncthreads();
  }
  float pw[16];
  #pragma unroll
  for (int j = 0; j < 16; j++) pw[j] = wv[j];        // w^{t+1} at t=0
  for (int t = 0; t < CH; t++) {
    float p = 0.f;
    #pragma unroll
    for (int j = 0; j < 16; j++) {
      p += rsh[t * SS + sg * 16 + j] * pw[j] * st[j];
      pw[j] *= wv[j];
    }
    part[sg * SS + o] = p;
    __syncthreads();
    if (tid < SS)
      Yb[(size_t)t * DD + tid] += part[tid] + part[SS + tid] + part[2 * SS + tid] + part[3 * SS + tid];
    __syncthreads();
  }
}

// ---- K8: GroupNorm(H groups) + *silu(g) + LayerNorm + act-quant for final proj ----
__global__ __launch_bounds__(256) void k_post(const float* __restrict__ Y,
                                              const float* __restrict__ G,
                                              const float* __restrict__ gn_g,
                                              const float* __restrict__ gn_b,
                                              const float* __restrict__ lg,
                                              const float* __restrict__ lb,
                                              bf16* __restrict__ xq4,
                                              float* __restrict__ ascale4) {
  __shared__ float red[256];
  __shared__ float ysh[DD];
  __shared__ float gmean[HH], grstd[HH];
  int m = blockIdx.x, tid = threadIdx.x;
  const float* Yr = Y + (size_t)m * DD;
  const float* Gr = G + (size_t)m * DD;
  #pragma unroll
  for (int j = 0; j < 4; j++) { int d = tid + j * 256; ysh[d] = Yr[d]; }
  __syncthreads();
  if (tid < HH) {
    float s = 0.f;
    for (int q2 = 0; q2 < SS; q2++) s += ysh[tid * SS + ((q2 + tid * 4) & 63)];
    float mn = s * (1.f / SS);
    float v2 = 0.f;
    for (int q2 = 0; q2 < SS; q2++) {
      float dv = ysh[tid * SS + ((q2 + tid * 4) & 63)] - mn; v2 += dv * dv;
    }
    gmean[tid] = mn;
    grstd[tid] = 1.f / sqrtf(v2 * (1.f / SS) + 1e-5f);
  }
  __syncthreads();
  float z[4];
  #pragma unroll
  for (int j = 0; j < 4; j++) {
    int d = tid + j * 256; int hh = d >> 6;
    float yn = (ysh[d] - gmean[hh]) * grstd[hh] * gn_g[d] + gn_b[d];
    float gv = Gr[d];
    z[j] = yn * (gv / (1.f + expf(-gv)));            // silu
  }
  float mean = block_sum(z[0] + z[1] + z[2] + z[3], red) * (1.f / DD);
  float var = 0.f;
  #pragma unroll
  for (int j = 0; j < 4; j++) { float dv = z[j] - mean; var += dv * dv; }
  var = block_sum(var, red) * (1.f / DD);
  float rstd = 1.f / sqrtf(var + 1e-5f);
  float ln[4]; float aabs = 0.f;
  #pragma unroll
  for (int j = 0; j < 4; j++) {
    int d = tid + j * 256;
    ln[j] = (z[j] - mean) * rstd * lg[d] + lb[d];
    aabs += fabsf(ln[j]);
  }
  float meanabs = block_sum(aabs, red) * (1.f / DD);
  float scale = fmaxf(meanabs, 1e-8f) * 2.5f * (1.f / 127.f);
  #pragma unroll
  for (int j = 0; j < 4; j++) {
    int d = tid + j * 256;
    xq4[(size_t)m * DD + d] =
        __float2bfloat16(rintf(fminf(fmaxf(ln[j] / scale, -127.f), 127.f)));
  }
  if (tid == 0) ascale4[m] = scale;
}

extern "C" void kernel_launch(void* const* d_in, const int* in_sizes, int n_in,
                              void* d_out, int out_size, void* d_ws, size_t ws_size,
                              hipStream_t stream) {
  // ALL inputs are float32 (verified R4); output float32.
  const float* x         = (const float*)d_in[0];
  const float* mu_r      = (const float*)d_in[1];
  const float* mu_k      = (const float*)d_in[2];
  const float* mu_v      = (const float*)d_in[3];
  const float* mu_g      = (const float*)d_in[4];
  const float* log_decay = (const float*)d_in[5];
  const float* u         = (const float*)d_in[6];
  const float* proj_w    = (const float*)d_in[7];
  const float* ln_g      = (const float*)d_in[8];
  const float* ln_b      = (const float*)d_in[9];
  const float* gn_g      = (const float*)d_in[10];
  const float* gn_b      = (const float*)d_in[11];
  float* out = (float*)d_out;

  // ---- workspace layout, ~234 MiB total ----
  // U region (64 MB) time-multiplexed:
  //   phase 1: xq slots 0..3 (bf16, 4 x 16 MB)   [k_prep_quant -> k_gemm]
  //   phase 2: Y  (f32, 32 MB) at U+0            [k_wkv_y -> k_post]
  //            xq4 (bf16, 16 MB) at U+32MB       [k_post -> k_gemm final]
  char* p = (char*)d_ws;
  float*  wscale = (float*)p;  p += 256;                         // 5 f32
  double* wpart  = (double*)p; p += 4096;                        // 5*64 f64
  bf16*   wq     = (bf16*)p;   p += (size_t)5 * DD * DD * 2;     // 10 MB
  float*  ascale = (float*)p;  p += (size_t)5 * M_ROWS * 4;      // 160 KB
  char*   U      = p;          p += (size_t)4 * M_ROWS * DD * 2; // 64 MB
  bf16*   xq     = (bf16*)U;
  float*  Y      = (float*)U;
  bf16*   xq4    = (bf16*)(U + (size_t)M_ROWS * DD * 4);         // U + 32 MB
  float*  rkvg   = (float*)p;  p += (size_t)4 * M_ROWS * DD * 4; // 128 MB
  float*  states = (float*)p;  p += (size_t)BB * HH * NC * SS * SS * 4; // 32 MB

  hipLaunchKernelGGL(k_wscale_part, dim3(5, 64), dim3(256), 0, stream, proj_w, wpart);
  hipLaunchKernelGGL(k_wscale_fin, dim3(5), dim3(64), 0, stream, wpart, wscale);
  hipLaunchKernelGGL(k_wquant, dim3((5 * DD * DD) / 256), dim3(256), 0, stream,
                     proj_w, wscale, wq);
  hipLaunchKernelGGL(k_prep_quant, dim3(M_ROWS, 4), dim3(256), 0, stream,
                     x, mu_r, mu_k, mu_v, mu_g, ln_g, ln_b, xq, ascale);
  hipLaunchKernelGGL(k_gemm, dim3(M_ROWS / 64, DD / 64, 4), dim3(256), 0,
                     stream, xq, wq, ascale, wscale, 0, rkvg);
  hipLaunchKernelGGL(k_inj, dim3(BB * HH * NC), dim3(256), 0, stream,
                     rkvg, log_decay, states);
  hipLaunchKernelGGL(k_scan, dim3(BB * HH), dim3(256), 0, stream, log_decay, states);
  hipLaunchKernelGGL(k_wkv_y, dim3(BB * HH * NC), dim3(256), 0, stream,
                     rkvg, log_decay, u, states, Y);
  hipLaunchKernelGGL(k_post, dim3(M_ROWS), dim3(256), 0, stream,
                     Y, rkvg + (size_t)3 * M_ROWS * DD, gn_g, gn_b,
                     ln_g + 4 * DD, ln_b + 4 * DD,
                     xq4, ascale + 4 * M_ROWS);
  hipLaunchKernelGGL(k_gemm, dim3(M_ROWS / 64, DD / 64, 1), dim3(256), 0,
                     stream, xq4, wq,
                     ascale + 4 * M_ROWS, wscale, 4, out);
}